// Round 6
// baseline (204.363 us; speedup 1.0000x reference)
//
#include <hip/hip_runtime.h>
#include <hip/hip_bf16.h>
#include <math.h>

#define T_SEQ 2048
#define DMODEL 2048
#define NHQ 16
#define NHK 8
#define HDIM 128
#define NL 4
#define ATT_SCALE 0.08838834764831845f  // 1/sqrt(128)

typedef __attribute__((ext_vector_type(8))) short bf16x8;
typedef __attribute__((ext_vector_type(4))) float f32x4;

__device__ __forceinline__ float bf2f(short u) {
    union { float f; unsigned int i; } x;
    x.i = ((unsigned int)(unsigned short)u) << 16;
    return x.f;
}
__device__ __forceinline__ unsigned short f2bf(float f) {
    __hip_bfloat16 h = __float2bfloat16(f);
    return *reinterpret_cast<unsigned short*>(&h);
}
__device__ __forceinline__ void gload16(const void* g, void* l) {
    __builtin_amdgcn_global_load_lds(
        (const __attribute__((address_space(1))) void*)g,
        (__attribute__((address_space(3))) void*)l, 16, 0, 0);
}

// ---------------------------------------------------------------------------
// Cast fp32 -> bf16, 8 elems/thread.
// ---------------------------------------------------------------------------
__global__ __launch_bounds__(256) void cast_f32_bf16(
    const float* __restrict__ s, unsigned short* __restrict__ d)
{
    int i = blockIdx.x * 256 + threadIdx.x;
    float4 a = ((const float4*)s)[2 * i];
    float4 b = ((const float4*)s)[2 * i + 1];
    bf16x8 v;
    v[0] = (short)f2bf(a.x); v[1] = (short)f2bf(a.y);
    v[2] = (short)f2bf(a.z); v[3] = (short)f2bf(a.w);
    v[4] = (short)f2bf(b.x); v[5] = (short)f2bf(b.y);
    v[6] = (short)f2bf(b.z); v[7] = (short)f2bf(b.w);
    ((bf16x8*)d)[i] = v;
}

// ---------------------------------------------------------------------------
// Transpose-cast: src fp32 [Ksrc][Nsrc] -> dst bf16 [Nsrc][Ksrc] @ dstOff.
// ---------------------------------------------------------------------------
__global__ __launch_bounds__(256) void tcast(
    const float* __restrict__ src, unsigned short* __restrict__ dst,
    int Nsrc, int Ksrc, int dstOff)
{
    __shared__ float ls[64][65];
    const int k0 = blockIdx.x * 64, n0 = blockIdx.y * 64;
    const int tid = threadIdx.x;
    #pragma unroll
    for (int it = 0; it < 4; ++it) {
        int fi = tid + it * 256;
        int r = fi >> 4;
        int c = (fi & 15) * 4;
        float4 v = *(const float4*)&src[(size_t)(k0 + r) * Nsrc + n0 + c];
        ls[r][c] = v.x; ls[r][c + 1] = v.y; ls[r][c + 2] = v.z; ls[r][c + 3] = v.w;
    }
    __syncthreads();
    int n = tid & 63, kc = tid >> 6;
    bf16x8 v0, v1;
    #pragma unroll
    for (int j = 0; j < 8; ++j) v0[j] = (short)f2bf(ls[kc * 16 + j][n]);
    #pragma unroll
    for (int j = 0; j < 8; ++j) v1[j] = (short)f2bf(ls[kc * 16 + 8 + j][n]);
    size_t drow = (size_t)(dstOff + n0 + n) * Ksrc + k0 + kc * 16;
    *(bf16x8*)&dst[drow] = v0;
    *(bf16x8*)&dst[drow + 8] = v1;
}

// ---------------------------------------------------------------------------
// bf16 MFMA GEMM (m97 structure), C = A * Bt^T. Unchanged from R5.
// ---------------------------------------------------------------------------
__global__ __launch_bounds__(256) void gemm_bt(
    const unsigned short* __restrict__ A, const unsigned short* __restrict__ Bt,
    float* __restrict__ Cf, unsigned short* __restrict__ Cq,
    unsigned short* __restrict__ Ck, unsigned short* __restrict__ Cv,
    int mode, int K)
{
    __shared__ char As[16384];
    __shared__ char Bs[16384];
    const int tid = threadIdx.x;
    const int wv = tid >> 6, lane = tid & 63;
    const int l15 = lane & 15, lg = lane >> 4;
    const int wm = wv >> 1, wn = wv & 1;
    const int bm = blockIdx.y * 128, bn = blockIdx.x * 128;

    f32x4 acc[4][4];
    #pragma unroll
    for (int i = 0; i < 4; ++i)
        #pragma unroll
        for (int j = 0; j < 4; ++j)
            acc[i][j] = (f32x4){0.f, 0.f, 0.f, 0.f};

    for (int k0 = 0; k0 < K; k0 += 64) {
        #pragma unroll
        for (int it = 0; it < 4; ++it) {
            int o = it * 4096 + tid * 16;
            int row = o >> 7;
            int sch = ((o >> 4) & 7) ^ (row & 7);
            gload16((const char*)A + ((((size_t)(bm + row) * K) + k0 + sch * 8) << 1),
                    As + it * 4096 + wv * 1024);
            gload16((const char*)Bt + ((((size_t)(bn + row) * K) + k0 + sch * 8) << 1),
                    Bs + it * 4096 + wv * 1024);
        }
        __syncthreads();
        #pragma unroll
        for (int kk = 0; kk < 2; ++kk) {
            bf16x8 av[4], bv[4];
            #pragma unroll
            for (int f = 0; f < 4; ++f) {
                int ra = wm * 64 + f * 16 + l15;
                av[f] = *(const bf16x8*)(As + ra * 128 + ((((kk << 2) | lg) ^ (ra & 7)) << 4));
                int rb = wn * 64 + f * 16 + l15;
                bv[f] = *(const bf16x8*)(Bs + rb * 128 + ((((kk << 2) | lg) ^ (rb & 7)) << 4));
            }
            #pragma unroll
            for (int mf = 0; mf < 4; ++mf)
                #pragma unroll
                for (int nf = 0; nf < 4; ++nf)
                    acc[mf][nf] = __builtin_amdgcn_mfma_f32_16x16x32_bf16(
                        av[mf], bv[nf], acc[mf][nf], 0, 0, 0);
        }
        __syncthreads();
    }

    #pragma unroll
    for (int mf = 0; mf < 4; ++mf) {
        int m0 = bm + wm * 64 + mf * 16 + lg * 4;
        #pragma unroll
        for (int nf = 0; nf < 4; ++nf) {
            int n0 = bn + wn * 64 + nf * 16 + l15;
            if (mode == 0) {
                #pragma unroll
                for (int r = 0; r < 4; ++r)
                    Cf[(size_t)(m0 + r) * 2048 + n0] = acc[mf][nf][r];
            } else if (n0 < 2048) {
                #pragma unroll
                for (int r = 0; r < 4; ++r)
                    Cq[(size_t)(m0 + r) * 2048 + n0] = f2bf(acc[mf][nf][r]);
            } else if (n0 < 3072) {
                #pragma unroll
                for (int r = 0; r < 4; ++r)
                    Ck[(size_t)(m0 + r) * 1024 + (n0 - 2048)] = f2bf(acc[mf][nf][r]);
            } else {
                ushort4 u;
                u.x = f2bf(acc[mf][nf][0]); u.y = f2bf(acc[mf][nf][1]);
                u.z = f2bf(acc[mf][nf][2]); u.w = f2bf(acc[mf][nf][3]);
                *(ushort4*)&Cv[(size_t)(n0 - 3072) * 2048 + m0] = u;
            }
        }
    }
}

// ---------------------------------------------------------------------------
// In-place RoPE on bf16 P[T][H*128].
// ---------------------------------------------------------------------------
__global__ __launch_bounds__(256) void rope_bf16(
    unsigned short* __restrict__ P, const float* __restrict__ cosT,
    const float* __restrict__ sinT, int H)
{
    int idx = blockIdx.x * 256 + threadIdx.x;
    int d = idx & 63;
    int h = (idx >> 6) % H;
    int t = idx / (64 * H);
    float c = cosT[t * HDIM + d];
    float s = sinT[t * HDIM + d];
    unsigned short* row = P + (size_t)t * (H * HDIM) + h * HDIM;
    float x0 = bf2f((short)row[d]), x1 = bf2f((short)row[d + 64]);
    row[d]      = f2bf(x0 * c - x1 * s);
    row[d + 64] = f2bf(x1 * c + x0 * s);
}

// ---------------------------------------------------------------------------
// MFMA flash attention, swapped-QK layout. R6: 32-key tiles, LDS 36KB ->
// 4 blocks/CU (16 waves); packed ds_write_b64 P-writes; defer-max (THR=8).
// XCD-pinned block encoding (bid&7 = hk), long blocks first, K/V dbuf with
// prefetch-before-compute and one barrier per tile.
// ---------------------------------------------------------------------------
__global__ __launch_bounds__(256, 4) void attn_mfma(
    const unsigned short* __restrict__ Qb, const unsigned short* __restrict__ Kb,
    const unsigned short* __restrict__ Vt,
    const float* __restrict__ Dk, const float* __restrict__ Dv,
    unsigned short* __restrict__ AO)
{
    __shared__ char Ks[2][8192];   // [32 keys][128 d] bf16, chunk ^= key&7
    __shared__ char Vs[2][8192];   // [128 d][32 keys] bf16 (64B rows), chunk ^= (d>>1)&3
    __shared__ char Ps[4096];      // 4 waves x [16 q][32 keys] bf16, chunk ^= (q>>1)&3

    const int bid = blockIdx.x;
    const int hk = bid & 7;                       // == XCD (round-robin dispatch)
    const int e = bid >> 3;
    const int hq = hk * 2 + (e & 1);
    const int q0 = (31 - (e >> 1)) * 64;          // long blocks first
    const int tid = threadIdx.x;
    const int wv = tid >> 6, lane = tid & 63;
    const int l15 = lane & 15, lg = lane >> 4;
    const size_t DSTRIDE = (size_t)NHK * T_SEQ * HDIM;

    const int tq = q0 + wv * 16 + l15;     // softmax-domain q row (per lane)
    const int qmax = q0 + wv * 16 + 15;    // wave's max q

    // Q B-frag: lane l15 = q col, k = d = c*32 + lg*8 + j
    bf16x8 qf[4];
    {
        const unsigned short* qrow = Qb + (size_t)tq * DMODEL + hq * HDIM;
        #pragma unroll
        for (int c = 0; c < 4; ++c)
            qf[c] = *(const bf16x8*)(qrow + c * 32 + lg * 8);
    }

    f32x4 oacc[8];
    #pragma unroll
    for (int dt = 0; dt < 8; ++dt) oacc[dt] = (f32x4){0.f, 0.f, 0.f, 0.f};
    float m = -1e30f, l = 0.f;

    // ---- staging: K[32][128] + Vt[128][32] (8KB each), pre-swizzled source ----
    #define STAGE(J0, BUF)                                                        \
        {                                                                         \
            _Pragma("unroll")                                                     \
            for (int it = 0; it < 2; ++it) {                                      \
                int o = it * 4096 + tid * 16;                                     \
                int rk = o >> 8, ck = (o >> 4) & 15;                              \
                gload16((const char*)Kb +                                         \
                        (((size_t)((J0) + rk) * 1024 + hk * 128 +                 \
                          ((ck ^ (rk & 7)) << 3)) << 1),                          \
                        Ks[BUF] + it * 4096 + wv * 1024);                         \
                int rv = o >> 6, cv = (o >> 4) & 3;                               \
                gload16((const char*)Vt +                                         \
                        (((size_t)(hk * 128 + rv) * 2048 + (J0) +                 \
                          ((cv ^ ((rv >> 1) & 3)) << 3)) << 1),                   \
                        Vs[BUF] + it * 4096 + wv * 1024);                         \
            }                                                                     \
        }

    STAGE(0, 0);
    __syncthreads();
    int buf = 0;

    const int jlast = q0 + 32;               // last tile start (keys q0+32..q0+63)
    for (int j0 = 0; j0 <= jlast; j0 += 32) {
        if (j0 < jlast) STAGE(j0 + 32, buf ^ 1);   // prefetch next tile

        if (j0 <= qmax) {
            const char* ksb = Ks[buf];
            const char* vsb = Vs[buf];
            // ---- S^T = K Q : 2 key-subtiles x 4 d-chunks ----
            float p[2][4];
            #pragma unroll
            for (int s = 0; s < 2; ++s) {
                if (j0 + s * 16 <= qmax) {
                    f32x4 sa = (f32x4){0.f, 0.f, 0.f, 0.f};
                    int row = s * 16 + l15;                 // key row (A-frag)
                    #pragma unroll
                    for (int c = 0; c < 4; ++c) {
                        int ch = (c * 4 + lg) ^ (row & 7);
                        bf16x8 kf = *(const bf16x8*)(ksb + row * 256 + ch * 16);
                        sa = __builtin_amdgcn_mfma_f32_16x16x32_bf16(kf, qf[c], sa, 0, 0, 0);
                    }
                    #pragma unroll
                    for (int r = 0; r < 4; ++r) {
                        int key = j0 + s * 16 + lg * 4 + r;
                        p[s][r] = (key <= tq) ? sa[r] * ATT_SCALE : -1e30f;
                    }
                } else {
                    #pragma unroll
                    for (int r = 0; r < 4; ++r) p[s][r] = -1e30f;
                }
            }
            // ---- online softmax with defer-max (THR=8) ----
            float vmax = p[0][0];
            #pragma unroll
            for (int s = 0; s < 2; ++s)
                #pragma unroll
                for (int r = 0; r < 4; ++r) vmax = fmaxf(vmax, p[s][r]);
            vmax = fmaxf(vmax, __shfl_xor(vmax, 16));
            vmax = fmaxf(vmax, __shfl_xor(vmax, 32));
            if (!__all(vmax <= m + 8.0f)) {
                float mn = fmaxf(m, vmax);
                float rs = __expf(m - mn);
                m = mn;
                l *= rs;
                float rs_o[4];
                #pragma unroll
                for (int r = 0; r < 4; ++r) rs_o[r] = __shfl(rs, lg * 4 + r);
                #pragma unroll
                for (int dt = 0; dt < 8; ++dt)
                    #pragma unroll
                    for (int r = 0; r < 4; ++r) oacc[dt][r] *= rs_o[r];
            }
            float sum = 0.f;
            #pragma unroll
            for (int s = 0; s < 2; ++s)
                #pragma unroll
                for (int r = 0; r < 4; ++r) {
                    float pe = __expf(p[s][r] - m);
                    p[s][r] = pe;
                    sum += pe;
                }
            sum += __shfl_xor(sum, 16);
            sum += __shfl_xor(sum, 32);
            l += sum;

            // ---- P -> per-wave LDS: pack 4 keys into one ds_write_b64 ----
            char* pw = Ps + wv * 1024;
            #pragma unroll
            for (int s = 0; s < 2; ++s) {
                unsigned int lo = (unsigned int)f2bf(p[s][0]) |
                                  ((unsigned int)f2bf(p[s][1]) << 16);
                unsigned int hi = (unsigned int)f2bf(p[s][2]) |
                                  ((unsigned int)f2bf(p[s][3]) << 16);
                int kc = s * 2 + (lg >> 1);               // key chunk 0..3
                int ch = kc ^ ((l15 >> 1) & 3);
                uint2 u = make_uint2(lo, hi);
                *(uint2*)(pw + l15 * 64 + ch * 16 + (lg & 1) * 8) = u;
            }
            asm volatile("" ::: "memory");
            // ---- PV: O += P V  (A = P rows q=l15, B = V cols d=l15) ----
            {
                bf16x8 pa = *(const bf16x8*)(pw + l15 * 64 + ((lg ^ ((l15 >> 1) & 3)) << 4));
                #pragma unroll
                for (int dt = 0; dt < 8; ++dt) {
                    int rv = dt * 16 + l15;
                    bf16x8 vf = *(const bf16x8*)(vsb + rv * 64 + ((lg ^ ((rv >> 1) & 3)) << 4));
                    oacc[dt] = __builtin_amdgcn_mfma_f32_16x16x32_bf16(pa, vf, oacc[dt], 0, 0, 0);
                }
            }
        }
        __syncthreads();   // drains prefetch + guards LDS reuse
        buf ^= 1;
    }

    // ---- depth slots (per-lane q = tq) ----
    float dl[NL];
    #pragma unroll
    for (int sl = 0; sl < NL; ++sl) {
        const float* kd = Dk + sl * DSTRIDE + ((size_t)hk * T_SEQ + tq) * HDIM;
        float a = 0.f;
        #pragma unroll
        for (int c = 0; c < 4; ++c) {
            const float* kc = kd + c * 32 + lg * 8;
            float4 v0 = *(const float4*)(kc);
            float4 v1 = *(const float4*)(kc + 4);
            a = fmaf(bf2f(qf[c][0]), v0.x, a);
            a = fmaf(bf2f(qf[c][1]), v0.y, a);
            a = fmaf(bf2f(qf[c][2]), v0.z, a);
            a = fmaf(bf2f(qf[c][3]), v0.w, a);
            a = fmaf(bf2f(qf[c][4]), v1.x, a);
            a = fmaf(bf2f(qf[c][5]), v1.y, a);
            a = fmaf(bf2f(qf[c][6]), v1.z, a);
            a = fmaf(bf2f(qf[c][7]), v1.w, a);
        }
        a += __shfl_xor(a, 16);
        a += __shfl_xor(a, 32);
        dl[sl] = a * ATT_SCALE;
    }
    float vm = fmaxf(fmaxf(dl[0], dl[1]), fmaxf(dl[2], dl[3]));
    float mn = fmaxf(m, vm);
    float rsd = __expf(m - mn);
    float pd[NL];
    #pragma unroll
    for (int sl = 0; sl < NL; ++sl) pd[sl] = __expf(dl[sl] - mn);
    l = l * rsd + (pd[0] + pd[1] + pd[2] + pd[3]);
    float linv = 1.f / l;
    float rs_o[4], li_o[4], pdo[NL][4];
    #pragma unroll
    for (int r = 0; r < 4; ++r) {
        rs_o[r] = __shfl(rsd, lg * 4 + r);
        li_o[r] = __shfl(linv, lg * 4 + r);
        #pragma unroll
        for (int sl = 0; sl < NL; ++sl) pdo[sl][r] = __shfl(pd[sl], lg * 4 + r);
    }
    #pragma unroll
    for (int r = 0; r < 4; ++r) {
        int t = q0 + wv * 16 + lg * 4 + r;
        #pragma unroll
        for (int dt = 0; dt < 8; ++dt) {
            const float* vb = Dv + ((size_t)hk * T_SEQ + t) * HDIM + dt * 16 + l15;
            float o = oacc[dt][r] * rs_o[r];
            o = fmaf(pdo[0][r], vb[0], o);
            o = fmaf(pdo[1][r], vb[DSTRIDE], o);
            o = fmaf(pdo[2][r], vb[2 * DSTRIDE], o);
            o = fmaf(pdo[3][r], vb[3 * DSTRIDE], o);
            oacc[dt][r] = o * li_o[r];
        }
    }
    #pragma unroll
    for (int r = 0; r < 4; ++r) {
        unsigned short* orow = AO + (size_t)(q0 + wv * 16 + lg * 4 + r) * DMODEL + hq * HDIM;
        #pragma unroll
        for (int dt = 0; dt < 8; ++dt)
            orow[dt * 16 + l15] = f2bf(oacc[dt][r]);
    }
    #undef STAGE
}

// ---------------------------------------------------------------------------
extern "C" void kernel_launch(void* const* d_in, const int* in_sizes, int n_in,
                              void* d_out, int out_size, void* d_ws, size_t ws_size,
                              hipStream_t stream) {
    const float* x    = (const float*)d_in[0];
    const float* dk   = (const float*)d_in[1];
    const float* dv   = (const float*)d_in[2];
    const float* cosT = (const float*)d_in[3];
    const float* sinT = (const float*)d_in[4];
    const float* Wq   = (const float*)d_in[5];
    const float* Wk   = (const float*)d_in[6];
    const float* Wv   = (const float*)d_in[7];
    const float* Wo   = (const float*)d_in[8];
    float* out = (float*)d_out;

    unsigned short* xb  = (unsigned short*)d_ws;
    unsigned short* Qb  = xb + (size_t)4 * 1024 * 1024;
    unsigned short* Kb  = Qb + (size_t)4 * 1024 * 1024;
    unsigned short* Vt  = Kb + (size_t)2 * 1024 * 1024;
    unsigned short* WTp = Vt + (size_t)2 * 1024 * 1024;
    unsigned short* WoT = WTp + (size_t)8 * 1024 * 1024;
    unsigned short* AOb = xb;   // alias: xb dead after proj GEMM

    cast_f32_bf16<<<dim3(2048), 256, 0, stream>>>(x, xb);
    tcast<<<dim3(32, 32), 256, 0, stream>>>(Wq, WTp, 2048, 2048, 0);
    tcast<<<dim3(32, 16), 256, 0, stream>>>(Wk, WTp, 1024, 2048, 2048);
    tcast<<<dim3(32, 16), 256, 0, stream>>>(Wv, WTp, 1024, 2048, 3072);
    tcast<<<dim3(32, 32), 256, 0, stream>>>(Wo, WoT, 2048, 2048, 0);
    gemm_bt<<<dim3(32, 16), 256, 0, stream>>>(xb, WTp, nullptr, Qb, Kb, Vt, 1, DMODEL);
    rope_bf16<<<dim3(T_SEQ * NHQ * 64 / 256), 256, 0, stream>>>(Qb, cosT, sinT, NHQ);
    rope_bf16<<<dim3(T_SEQ * NHK * 64 / 256), 256, 0, stream>>>(Kb, cosT, sinT, NHK);
    attn_mfma<<<dim3(512), 256, 0, stream>>>(Qb, Kb, Vt, dk, dv, AOb);
    gemm_bt<<<dim3(16, 16), 256, 0, stream>>>(AOb, WoT, out, nullptr, nullptr, nullptr, 0, DMODEL);
}

// Round 7
// 201.361 us; speedup vs baseline: 1.0149x; 1.0149x over previous
//
#include <hip/hip_runtime.h>
#include <hip/hip_bf16.h>
#include <math.h>

#define T_SEQ 2048
#define DMODEL 2048
#define NHQ 16
#define NHK 8
#define HDIM 128
#define NL 4
#define ATT_SCALE 0.08838834764831845f  // 1/sqrt(128)

typedef __attribute__((ext_vector_type(8))) short bf16x8;
typedef __attribute__((ext_vector_type(4))) float f32x4;

__device__ __forceinline__ float bf2f(short u) {
    union { float f; unsigned int i; } x;
    x.i = ((unsigned int)(unsigned short)u) << 16;
    return x.f;
}
__device__ __forceinline__ unsigned short f2bf(float f) {
    __hip_bfloat16 h = __float2bfloat16(f);
    return *reinterpret_cast<unsigned short*>(&h);
}
__device__ __forceinline__ void gload16(const void* g, void* l) {
    __builtin_amdgcn_global_load_lds(
        (const __attribute__((address_space(1))) void*)g,
        (__attribute__((address_space(3))) void*)l, 16, 0, 0);
}

// ---------------------------------------------------------------------------
// Cast fp32 -> bf16, 8 elems/thread.
// ---------------------------------------------------------------------------
__global__ __launch_bounds__(256) void cast_f32_bf16(
    const float* __restrict__ s, unsigned short* __restrict__ d)
{
    int i = blockIdx.x * 256 + threadIdx.x;
    float4 a = ((const float4*)s)[2 * i];
    float4 b = ((const float4*)s)[2 * i + 1];
    bf16x8 v;
    v[0] = (short)f2bf(a.x); v[1] = (short)f2bf(a.y);
    v[2] = (short)f2bf(a.z); v[3] = (short)f2bf(a.w);
    v[4] = (short)f2bf(b.x); v[5] = (short)f2bf(b.y);
    v[6] = (short)f2bf(b.z); v[7] = (short)f2bf(b.w);
    ((bf16x8*)d)[i] = v;
}

// ---------------------------------------------------------------------------
// Transpose-cast: src fp32 [Ksrc][Nsrc] -> dst bf16 [Nsrc][Ksrc] @ dstOff.
// ---------------------------------------------------------------------------
__global__ __launch_bounds__(256) void tcast(
    const float* __restrict__ src, unsigned short* __restrict__ dst,
    int Nsrc, int Ksrc, int dstOff)
{
    __shared__ float ls[64][65];
    const int k0 = blockIdx.x * 64, n0 = blockIdx.y * 64;
    const int tid = threadIdx.x;
    #pragma unroll
    for (int it = 0; it < 4; ++it) {
        int fi = tid + it * 256;
        int r = fi >> 4;
        int c = (fi & 15) * 4;
        float4 v = *(const float4*)&src[(size_t)(k0 + r) * Nsrc + n0 + c];
        ls[r][c] = v.x; ls[r][c + 1] = v.y; ls[r][c + 2] = v.z; ls[r][c + 3] = v.w;
    }
    __syncthreads();
    int n = tid & 63, kc = tid >> 6;
    bf16x8 v0, v1;
    #pragma unroll
    for (int j = 0; j < 8; ++j) v0[j] = (short)f2bf(ls[kc * 16 + j][n]);
    #pragma unroll
    for (int j = 0; j < 8; ++j) v1[j] = (short)f2bf(ls[kc * 16 + 8 + j][n]);
    size_t drow = (size_t)(dstOff + n0 + n) * Ksrc + k0 + kc * 16;
    *(bf16x8*)&dst[drow] = v0;
    *(bf16x8*)&dst[drow + 8] = v1;
}

// ---------------------------------------------------------------------------
// bf16 MFMA GEMM (m97 structure), C = A * Bt^T. Unchanged from R6.
// ---------------------------------------------------------------------------
__global__ __launch_bounds__(256) void gemm_bt(
    const unsigned short* __restrict__ A, const unsigned short* __restrict__ Bt,
    float* __restrict__ Cf, unsigned short* __restrict__ Cq,
    unsigned short* __restrict__ Ck, unsigned short* __restrict__ Cv,
    int mode, int K)
{
    __shared__ char As[16384];
    __shared__ char Bs[16384];
    const int tid = threadIdx.x;
    const int wv = tid >> 6, lane = tid & 63;
    const int l15 = lane & 15, lg = lane >> 4;
    const int wm = wv >> 1, wn = wv & 1;
    const int bm = blockIdx.y * 128, bn = blockIdx.x * 128;

    f32x4 acc[4][4];
    #pragma unroll
    for (int i = 0; i < 4; ++i)
        #pragma unroll
        for (int j = 0; j < 4; ++j)
            acc[i][j] = (f32x4){0.f, 0.f, 0.f, 0.f};

    for (int k0 = 0; k0 < K; k0 += 64) {
        #pragma unroll
        for (int it = 0; it < 4; ++it) {
            int o = it * 4096 + tid * 16;
            int row = o >> 7;
            int sch = ((o >> 4) & 7) ^ (row & 7);
            gload16((const char*)A + ((((size_t)(bm + row) * K) + k0 + sch * 8) << 1),
                    As + it * 4096 + wv * 1024);
            gload16((const char*)Bt + ((((size_t)(bn + row) * K) + k0 + sch * 8) << 1),
                    Bs + it * 4096 + wv * 1024);
        }
        __syncthreads();
        #pragma unroll
        for (int kk = 0; kk < 2; ++kk) {
            bf16x8 av[4], bv[4];
            #pragma unroll
            for (int f = 0; f < 4; ++f) {
                int ra = wm * 64 + f * 16 + l15;
                av[f] = *(const bf16x8*)(As + ra * 128 + ((((kk << 2) | lg) ^ (ra & 7)) << 4));
                int rb = wn * 64 + f * 16 + l15;
                bv[f] = *(const bf16x8*)(Bs + rb * 128 + ((((kk << 2) | lg) ^ (rb & 7)) << 4));
            }
            #pragma unroll
            for (int mf = 0; mf < 4; ++mf)
                #pragma unroll
                for (int nf = 0; nf < 4; ++nf)
                    acc[mf][nf] = __builtin_amdgcn_mfma_f32_16x16x32_bf16(
                        av[mf], bv[nf], acc[mf][nf], 0, 0, 0);
        }
        __syncthreads();
    }

    #pragma unroll
    for (int mf = 0; mf < 4; ++mf) {
        int m0 = bm + wm * 64 + mf * 16 + lg * 4;
        #pragma unroll
        for (int nf = 0; nf < 4; ++nf) {
            int n0 = bn + wn * 64 + nf * 16 + l15;
            if (mode == 0) {
                #pragma unroll
                for (int r = 0; r < 4; ++r)
                    Cf[(size_t)(m0 + r) * 2048 + n0] = acc[mf][nf][r];
            } else if (n0 < 2048) {
                #pragma unroll
                for (int r = 0; r < 4; ++r)
                    Cq[(size_t)(m0 + r) * 2048 + n0] = f2bf(acc[mf][nf][r]);
            } else if (n0 < 3072) {
                #pragma unroll
                for (int r = 0; r < 4; ++r)
                    Ck[(size_t)(m0 + r) * 1024 + (n0 - 2048)] = f2bf(acc[mf][nf][r]);
            } else {
                ushort4 u;
                u.x = f2bf(acc[mf][nf][0]); u.y = f2bf(acc[mf][nf][1]);
                u.z = f2bf(acc[mf][nf][2]); u.w = f2bf(acc[mf][nf][3]);
                *(ushort4*)&Cv[(size_t)(n0 - 3072) * 2048 + m0] = u;
            }
        }
    }
}

// ---------------------------------------------------------------------------
// In-place RoPE on bf16 P[T][H*128].
// ---------------------------------------------------------------------------
__global__ __launch_bounds__(256) void rope_bf16(
    unsigned short* __restrict__ P, const float* __restrict__ cosT,
    const float* __restrict__ sinT, int H)
{
    int idx = blockIdx.x * 256 + threadIdx.x;
    int d = idx & 63;
    int h = (idx >> 6) % H;
    int t = idx / (64 * H);
    float c = cosT[t * HDIM + d];
    float s = sinT[t * HDIM + d];
    unsigned short* row = P + (size_t)t * (H * HDIM) + h * HDIM;
    float x0 = bf2f((short)row[d]), x1 = bf2f((short)row[d + 64]);
    row[d]      = f2bf(x0 * c - x1 * s);
    row[d + 64] = f2bf(x1 * c + x0 * s);
}

// ---------------------------------------------------------------------------
// Split-K flash attention (flash-decode style). Each block = one 512-key
// segment of one (hq, 64-q-tile): 1280 near-uniform blocks, XCD-pinned by hk.
// Writes unnormalized partials: O (bf16 [64][128]) + per-row (m,l) f32.
// Segment decode: per head, si in [0,80): qt 0..7 ->1 seg, 8..15 ->2,
// 16..23 ->3, 24..31 ->4. si descending so short segments land in the tail.
// ---------------------------------------------------------------------------
__global__ __launch_bounds__(256, 4) void attn_seg(
    const unsigned short* __restrict__ Qb, const unsigned short* __restrict__ Kb,
    const unsigned short* __restrict__ Vt,
    unsigned short* __restrict__ Opart, float2* __restrict__ mlpart)
{
    __shared__ char Ks[2][8192];   // [32 keys][128 d] bf16, chunk ^= key&7
    __shared__ char Vs[2][8192];   // [128 d][32 keys] bf16 (64B rows), chunk ^= (d>>1)&3
    __shared__ char Ps[4096];      // 4 waves x [16 q][32 keys] bf16, chunk ^= (q>>1)&3

    const int bid = blockIdx.x;
    const int hk = bid & 7;                       // == XCD (round-robin dispatch)
    const int idx = bid >> 3;                     // 0..159
    const int hq = hk * 2 + (idx & 1);
    const int si = 79 - (idx >> 1);               // long segments first
    int qt, seg;
    if (si < 8)       { qt = si;            seg = 0; }
    else if (si < 24) { int v = si - 8;  qt = 8  + (v >> 1); seg = v & 1; }
    else if (si < 48) { int v = si - 24; int q3 = v / 3; qt = 16 + q3; seg = v - q3 * 3; }
    else              { int v = si - 48; qt = 24 + (v >> 2); seg = v & 3; }
    const int q0 = qt * 64;
    const int keys = q0 + 64;
    const int jbeg = seg * 512;
    const int jend = min(jbeg + 512, keys);

    const int tid = threadIdx.x;
    const int wv = tid >> 6, lane = tid & 63;
    const int l15 = lane & 15, lg = lane >> 4;

    const int tq = q0 + wv * 16 + l15;     // softmax-domain q row (per lane)
    const int qmax = q0 + wv * 16 + 15;    // wave's max q

    // Q B-frag: lane l15 = q col, k = d = c*32 + lg*8 + j
    bf16x8 qf[4];
    {
        const unsigned short* qrow = Qb + (size_t)tq * DMODEL + hq * HDIM;
        #pragma unroll
        for (int c = 0; c < 4; ++c)
            qf[c] = *(const bf16x8*)(qrow + c * 32 + lg * 8);
    }

    f32x4 oacc[8];
    #pragma unroll
    for (int dt = 0; dt < 8; ++dt) oacc[dt] = (f32x4){0.f, 0.f, 0.f, 0.f};
    float m = -1e30f, l = 0.f;

    #define STAGE(J0, BUF)                                                        \
        {                                                                         \
            _Pragma("unroll")                                                     \
            for (int it = 0; it < 2; ++it) {                                      \
                int o = it * 4096 + tid * 16;                                     \
                int rk = o >> 8, ck = (o >> 4) & 15;                              \
                gload16((const char*)Kb +                                         \
                        (((size_t)((J0) + rk) * 1024 + hk * 128 +                 \
                          ((ck ^ (rk & 7)) << 3)) << 1),                          \
                        Ks[BUF] + it * 4096 + wv * 1024);                         \
                int rv = o >> 6, cv = (o >> 4) & 3;                               \
                gload16((const char*)Vt +                                         \
                        (((size_t)(hk * 128 + rv) * 2048 + (J0) +                 \
                          ((cv ^ ((rv >> 1) & 3)) << 3)) << 1),                   \
                        Vs[BUF] + it * 4096 + wv * 1024);                         \
            }                                                                     \
        }

    STAGE(jbeg, 0);
    __syncthreads();
    int buf = 0;

    for (int j0 = jbeg; j0 < jend; j0 += 32) {
        if (j0 + 32 < jend) STAGE(j0 + 32, buf ^ 1);   // prefetch next tile

        if (j0 <= qmax) {
            const char* ksb = Ks[buf];
            const char* vsb = Vs[buf];
            // ---- S^T = K Q : 2 key-subtiles x 4 d-chunks ----
            float p[2][4];
            #pragma unroll
            for (int s = 0; s < 2; ++s) {
                if (j0 + s * 16 <= qmax) {
                    f32x4 sa = (f32x4){0.f, 0.f, 0.f, 0.f};
                    int row = s * 16 + l15;                 // key row (A-frag)
                    #pragma unroll
                    for (int c = 0; c < 4; ++c) {
                        int ch = (c * 4 + lg) ^ (row & 7);
                        bf16x8 kf = *(const bf16x8*)(ksb + row * 256 + ch * 16);
                        sa = __builtin_amdgcn_mfma_f32_16x16x32_bf16(kf, qf[c], sa, 0, 0, 0);
                    }
                    #pragma unroll
                    for (int r = 0; r < 4; ++r) {
                        int key = j0 + s * 16 + lg * 4 + r;
                        p[s][r] = (key <= tq) ? sa[r] * ATT_SCALE : -1e30f;
                    }
                } else {
                    #pragma unroll
                    for (int r = 0; r < 4; ++r) p[s][r] = -1e30f;
                }
            }
            // ---- online softmax with defer-max (THR=8) ----
            float vmax = p[0][0];
            #pragma unroll
            for (int s = 0; s < 2; ++s)
                #pragma unroll
                for (int r = 0; r < 4; ++r) vmax = fmaxf(vmax, p[s][r]);
            vmax = fmaxf(vmax, __shfl_xor(vmax, 16));
            vmax = fmaxf(vmax, __shfl_xor(vmax, 32));
            if (!__all(vmax <= m + 8.0f)) {
                float mn = fmaxf(m, vmax);
                float rs = __expf(m - mn);
                m = mn;
                l *= rs;
                float rs_o[4];
                #pragma unroll
                for (int r = 0; r < 4; ++r) rs_o[r] = __shfl(rs, lg * 4 + r);
                #pragma unroll
                for (int dt = 0; dt < 8; ++dt)
                    #pragma unroll
                    for (int r = 0; r < 4; ++r) oacc[dt][r] *= rs_o[r];
            }
            float sum = 0.f;
            #pragma unroll
            for (int s = 0; s < 2; ++s)
                #pragma unroll
                for (int r = 0; r < 4; ++r) {
                    float pe = __expf(p[s][r] - m);
                    p[s][r] = pe;
                    sum += pe;
                }
            sum += __shfl_xor(sum, 16);
            sum += __shfl_xor(sum, 32);
            l += sum;

            // ---- P -> per-wave LDS: pack 4 keys into one ds_write_b64 ----
            char* pw = Ps + wv * 1024;
            #pragma unroll
            for (int s = 0; s < 2; ++s) {
                unsigned int lo = (unsigned int)f2bf(p[s][0]) |
                                  ((unsigned int)f2bf(p[s][1]) << 16);
                unsigned int hi = (unsigned int)f2bf(p[s][2]) |
                                  ((unsigned int)f2bf(p[s][3]) << 16);
                int kc = s * 2 + (lg >> 1);               // key chunk 0..3
                int ch = kc ^ ((l15 >> 1) & 3);
                uint2 u = make_uint2(lo, hi);
                *(uint2*)(pw + l15 * 64 + ch * 16 + (lg & 1) * 8) = u;
            }
            asm volatile("" ::: "memory");
            // ---- PV: O += P V ----
            {
                bf16x8 pa = *(const bf16x8*)(pw + l15 * 64 + ((lg ^ ((l15 >> 1) & 3)) << 4));
                #pragma unroll
                for (int dt = 0; dt < 8; ++dt) {
                    int rv = dt * 16 + l15;
                    bf16x8 vf = *(const bf16x8*)(vsb + rv * 64 + ((lg ^ ((rv >> 1) & 3)) << 4));
                    oacc[dt] = __builtin_amdgcn_mfma_f32_16x16x32_bf16(pa, vf, oacc[dt], 0, 0, 0);
                }
            }
        }
        __syncthreads();   // drains prefetch + guards LDS reuse
        buf ^= 1;
    }

    // ---- write partials (unnormalized O bf16, per-row m/l f32) ----
    const int p = (hq * 32 + qt) * 4 + seg;
    unsigned short* op = Opart + (size_t)p * 8192;
    #pragma unroll
    for (int r = 0; r < 4; ++r) {
        unsigned short* orow = op + (wv * 16 + lg * 4 + r) * 128;
        #pragma unroll
        for (int dt = 0; dt < 8; ++dt)
            orow[dt * 16 + l15] = f2bf(oacc[dt][r]);
    }
    if (lg == 0) mlpart[p * 64 + wv * 16 + l15] = make_float2(m, l);
    #undef STAGE
}

// ---------------------------------------------------------------------------
// Combine: merge <=4 segment partials per (hq, q-tile), fold in the 4 depth
// slots (exact joint softmax), normalize, write bf16 AO.
// Block = (hq, qt): 4 waves x 16 rows; lane (l15,lg) owns row wv*16+l15,
// d-range [lg*32, lg*32+32).
// ---------------------------------------------------------------------------
__global__ __launch_bounds__(256) void attn_combine(
    const unsigned short* __restrict__ Qb,
    const unsigned short* __restrict__ Opart, const float2* __restrict__ mlpart,
    const float* __restrict__ Dk, const float* __restrict__ Dv,
    unsigned short* __restrict__ AO)
{
    const int bid = blockIdx.x;                 // 512
    const int hk = bid & 7;
    const int hq = hk * 2 + ((bid >> 3) & 1);
    const int qt = bid >> 4;                    // 0..31
    const int nseg = (qt >> 3) + 1;
    const int pbase = (hq * 32 + qt) * 4;
    const int tid = threadIdx.x;
    const int wv = tid >> 6, lane = tid & 63;
    const int l15 = lane & 15, lg = lane >> 4;
    const size_t DSTRIDE = (size_t)NHK * T_SEQ * HDIM;

    const int row = wv * 16 + l15;              // 0..63
    const int t = qt * 64 + row;

    // Q row (for depth logits): chunk c*32 + lg*8
    bf16x8 qf[4];
    {
        const unsigned short* qrow = Qb + (size_t)t * DMODEL + hq * HDIM;
        #pragma unroll
        for (int c = 0; c < 4; ++c)
            qf[c] = *(const bf16x8*)(qrow + c * 32 + lg * 8);
    }
    // depth logits (full dot via shfl reduce over lg)
    float dl[NL];
    #pragma unroll
    for (int sl = 0; sl < NL; ++sl) {
        const float* kd = Dk + sl * DSTRIDE + ((size_t)hk * T_SEQ + t) * HDIM;
        float a = 0.f;
        #pragma unroll
        for (int c = 0; c < 4; ++c) {
            const float* kc = kd + c * 32 + lg * 8;
            float4 v0 = *(const float4*)(kc);
            float4 v1 = *(const float4*)(kc + 4);
            a = fmaf(bf2f(qf[c][0]), v0.x, a);
            a = fmaf(bf2f(qf[c][1]), v0.y, a);
            a = fmaf(bf2f(qf[c][2]), v0.z, a);
            a = fmaf(bf2f(qf[c][3]), v0.w, a);
            a = fmaf(bf2f(qf[c][4]), v1.x, a);
            a = fmaf(bf2f(qf[c][5]), v1.y, a);
            a = fmaf(bf2f(qf[c][6]), v1.z, a);
            a = fmaf(bf2f(qf[c][7]), v1.w, a);
        }
        a += __shfl_xor(a, 16);
        a += __shfl_xor(a, 32);
        dl[sl] = a * ATT_SCALE;
    }

    // segment stats
    float mi[4], li[4];
    float M = -1e30f;
    for (int i = 0; i < nseg; ++i) {
        float2 v = mlpart[(pbase + i) * 64 + row];
        mi[i] = v.x; li[i] = v.y;
        M = fmaxf(M, v.x);
    }
    float M2 = fmaxf(M, fmaxf(fmaxf(dl[0], dl[1]), fmaxf(dl[2], dl[3])));
    float L = 0.f, w[4], pd[NL];
    for (int i = 0; i < nseg; ++i) {
        w[i] = __expf(mi[i] - M2);
        L += w[i] * li[i];
    }
    #pragma unroll
    for (int sl = 0; sl < NL; ++sl) {
        pd[sl] = __expf(dl[sl] - M2);
        L += pd[sl];
    }
    float linv = 1.f / L;

    // accumulate O over segments + depth values
    float o[32];
    #pragma unroll
    for (int j = 0; j < 32; ++j) o[j] = 0.f;
    for (int i = 0; i < nseg; ++i) {
        const unsigned short* opr = Opart + (size_t)(pbase + i) * 8192 + row * 128 + lg * 32;
        #pragma unroll
        for (int c = 0; c < 4; ++c) {
            bf16x8 v = *(const bf16x8*)(opr + c * 8);
            #pragma unroll
            for (int j = 0; j < 8; ++j)
                o[c * 8 + j] = fmaf(w[i], bf2f(v[j]), o[c * 8 + j]);
        }
    }
    #pragma unroll
    for (int sl = 0; sl < NL; ++sl) {
        const float* vb = Dv + sl * DSTRIDE + ((size_t)hk * T_SEQ + t) * HDIM + lg * 32;
        #pragma unroll
        for (int c = 0; c < 8; ++c) {
            float4 v = *(const float4*)(vb + c * 4);
            o[c * 4 + 0] = fmaf(pd[sl], v.x, o[c * 4 + 0]);
            o[c * 4 + 1] = fmaf(pd[sl], v.y, o[c * 4 + 1]);
            o[c * 4 + 2] = fmaf(pd[sl], v.z, o[c * 4 + 2]);
            o[c * 4 + 3] = fmaf(pd[sl], v.w, o[c * 4 + 3]);
        }
    }
    unsigned short* orow = AO + (size_t)t * DMODEL + hq * HDIM + lg * 32;
    #pragma unroll
    for (int c = 0; c < 4; ++c) {
        bf16x8 v;
        #pragma unroll
        for (int j = 0; j < 8; ++j) v[j] = (short)f2bf(o[c * 8 + j] * linv);
        *(bf16x8*)(orow + c * 8) = v;
    }
}

// ---------------------------------------------------------------------------
extern "C" void kernel_launch(void* const* d_in, const int* in_sizes, int n_in,
                              void* d_out, int out_size, void* d_ws, size_t ws_size,
                              hipStream_t stream) {
    const float* x    = (const float*)d_in[0];
    const float* dk   = (const float*)d_in[1];
    const float* dv   = (const float*)d_in[2];
    const float* cosT = (const float*)d_in[3];
    const float* sinT = (const float*)d_in[4];
    const float* Wq   = (const float*)d_in[5];
    const float* Wk   = (const float*)d_in[6];
    const float* Wv   = (const float*)d_in[7];
    const float* Wo   = (const float*)d_in[8];
    float* out = (float*)d_out;

    // ws layout (ushort units unless noted): xb/AOb 4M | Qb 4M | Kb 2M | Vt 2M
    // | WTp 8M | WoT 4M | Opart 16.78M | mlpart 1MB   (~81 MB total)
    unsigned short* xb    = (unsigned short*)d_ws;
    unsigned short* Qb    = xb + (size_t)4 * 1024 * 1024;
    unsigned short* Kb    = Qb + (size_t)4 * 1024 * 1024;
    unsigned short* Vt    = Kb + (size_t)2 * 1024 * 1024;
    unsigned short* WTp   = Vt + (size_t)2 * 1024 * 1024;
    unsigned short* WoT   = WTp + (size_t)8 * 1024 * 1024;
    unsigned short* Opart = WoT + (size_t)4 * 1024 * 1024;
    float2* mlpart = (float2*)(Opart + (size_t)2048 * 8192);
    unsigned short* AOb = xb;   // alias: xb dead after proj GEMM

    cast_f32_bf16<<<dim3(2048), 256, 0, stream>>>(x, xb);
    tcast<<<dim3(32, 32), 256, 0, stream>>>(Wq, WTp, 2048, 2048, 0);
    tcast<<<dim3(32, 16), 256, 0, stream>>>(Wk, WTp, 1024, 2048, 2048);
    tcast<<<dim3(32, 16), 256, 0, stream>>>(Wv, WTp, 1024, 2048, 3072);
    tcast<<<dim3(32, 32), 256, 0, stream>>>(Wo, WoT, 2048, 2048, 0);
    gemm_bt<<<dim3(32, 16), 256, 0, stream>>>(xb, WTp, nullptr, Qb, Kb, Vt, 1, DMODEL);
    rope_bf16<<<dim3(T_SEQ * NHQ * 64 / 256), 256, 0, stream>>>(Qb, cosT, sinT, NHQ);
    rope_bf16<<<dim3(T_SEQ * NHK * 64 / 256), 256, 0, stream>>>(Kb, cosT, sinT, NHK);
    attn_seg<<<dim3(1280), 256, 0, stream>>>(Qb, Kb, Vt, Opart, mlpart);
    attn_combine<<<dim3(512), 256, 0, stream>>>(Qb, Opart, mlpart, dk, dv, AOb);
    gemm_bt<<<dim3(16, 16), 256, 0, stream>>>(AOb, WoT, out, nullptr, nullptr, nullptr, 0, DMODEL);
}

// Round 8
// 177.169 us; speedup vs baseline: 1.1535x; 1.1365x over previous
//
#include <hip/hip_runtime.h>
#include <hip/hip_bf16.h>
#include <math.h>

#define T_SEQ 2048
#define DMODEL 2048
#define NHQ 16
#define NHK 8
#define HDIM 128
#define NL 4
#define ATT_SCALE 0.08838834764831845f  // 1/sqrt(128)

typedef __attribute__((ext_vector_type(8))) short bf16x8;
typedef __attribute__((ext_vector_type(4))) float f32x4;

__device__ __forceinline__ float bf2f(short u) {
    union { float f; unsigned int i; } x;
    x.i = ((unsigned int)(unsigned short)u) << 16;
    return x.f;
}
__device__ __forceinline__ unsigned short f2bf(float f) {
    __hip_bfloat16 h = __float2bfloat16(f);
    return *reinterpret_cast<unsigned short*>(&h);
}
__device__ __forceinline__ void gload16(const void* g, void* l) {
    __builtin_amdgcn_global_load_lds(
        (const __attribute__((address_space(1))) void*)g,
        (__attribute__((address_space(3))) void*)l, 16, 0, 0);
}

// ---------------------------------------------------------------------------
// Cast fp32 -> bf16, 8 elems/thread.
// ---------------------------------------------------------------------------
__global__ __launch_bounds__(256) void cast_f32_bf16(
    const float* __restrict__ s, unsigned short* __restrict__ d)
{
    int i = blockIdx.x * 256 + threadIdx.x;
    float4 a = ((const float4*)s)[2 * i];
    float4 b = ((const float4*)s)[2 * i + 1];
    bf16x8 v;
    v[0] = (short)f2bf(a.x); v[1] = (short)f2bf(a.y);
    v[2] = (short)f2bf(a.z); v[3] = (short)f2bf(a.w);
    v[4] = (short)f2bf(b.x); v[5] = (short)f2bf(b.y);
    v[6] = (short)f2bf(b.z); v[7] = (short)f2bf(b.w);
    ((bf16x8*)d)[i] = v;
}

// ---------------------------------------------------------------------------
// Transpose-cast: src fp32 [Ksrc][Nsrc] -> dst bf16 [Nsrc][Ksrc] @ dstOff.
// ---------------------------------------------------------------------------
__global__ __launch_bounds__(256) void tcast(
    const float* __restrict__ src, unsigned short* __restrict__ dst,
    int Nsrc, int Ksrc, int dstOff)
{
    __shared__ float ls[64][65];
    const int k0 = blockIdx.x * 64, n0 = blockIdx.y * 64;
    const int tid = threadIdx.x;
    #pragma unroll
    for (int it = 0; it < 4; ++it) {
        int fi = tid + it * 256;
        int r = fi >> 4;
        int c = (fi & 15) * 4;
        float4 v = *(const float4*)&src[(size_t)(k0 + r) * Nsrc + n0 + c];
        ls[r][c] = v.x; ls[r][c + 1] = v.y; ls[r][c + 2] = v.z; ls[r][c + 3] = v.w;
    }
    __syncthreads();
    int n = tid & 63, kc = tid >> 6;
    bf16x8 v0, v1;
    #pragma unroll
    for (int j = 0; j < 8; ++j) v0[j] = (short)f2bf(ls[kc * 16 + j][n]);
    #pragma unroll
    for (int j = 0; j < 8; ++j) v1[j] = (short)f2bf(ls[kc * 16 + 8 + j][n]);
    size_t drow = (size_t)(dstOff + n0 + n) * Ksrc + k0 + kc * 16;
    *(bf16x8*)&dst[drow] = v0;
    *(bf16x8*)&dst[drow + 8] = v1;
}

// ---------------------------------------------------------------------------
// bf16 MFMA GEMM, R8: 128x64 tile (LDS 24KB) -> 2x grid vs 128x128, fixing
// the 1-2 blk/CU latency exposure at these small shapes. 4 waves, wave tile
// 64x32 (4x2 16x16 frags). Same both-sides XOR swizzle + gload16 staging.
// mode 0: f32 C row-major. mode 1: fused proj epilogue over N=4096.
// ---------------------------------------------------------------------------
__global__ __launch_bounds__(256, 4) void gemm_bt(
    const unsigned short* __restrict__ A, const unsigned short* __restrict__ Bt,
    float* __restrict__ Cf, unsigned short* __restrict__ Cq,
    unsigned short* __restrict__ Ck, unsigned short* __restrict__ Cv,
    int mode, int K)
{
    __shared__ char As[16384];   // [128 m][64 k] bf16, chunk ^= row&7
    __shared__ char Bs[8192];    // [64 n][64 k] bf16, chunk ^= row&7
    const int tid = threadIdx.x;
    const int wv = tid >> 6, lane = tid & 63;
    const int l15 = lane & 15, lg = lane >> 4;
    const int wm = wv >> 1, wn = wv & 1;
    const int bm = blockIdx.y * 128, bn = blockIdx.x * 64;

    f32x4 acc[4][2];
    #pragma unroll
    for (int i = 0; i < 4; ++i)
        #pragma unroll
        for (int j = 0; j < 2; ++j)
            acc[i][j] = (f32x4){0.f, 0.f, 0.f, 0.f};

    for (int k0 = 0; k0 < K; k0 += 64) {
        #pragma unroll
        for (int it = 0; it < 4; ++it) {
            int o = it * 4096 + tid * 16;
            int row = o >> 7;
            int sch = ((o >> 4) & 7) ^ (row & 7);
            gload16((const char*)A + ((((size_t)(bm + row) * K) + k0 + sch * 8) << 1),
                    As + it * 4096 + wv * 1024);
        }
        #pragma unroll
        for (int it = 0; it < 2; ++it) {
            int o = it * 4096 + tid * 16;
            int row = o >> 7;
            int sch = ((o >> 4) & 7) ^ (row & 7);
            gload16((const char*)Bt + ((((size_t)(bn + row) * K) + k0 + sch * 8) << 1),
                    Bs + it * 4096 + wv * 1024);
        }
        __syncthreads();
        #pragma unroll
        for (int kk = 0; kk < 2; ++kk) {
            bf16x8 av[4], bv[2];
            #pragma unroll
            for (int f = 0; f < 4; ++f) {
                int ra = wm * 64 + f * 16 + l15;
                av[f] = *(const bf16x8*)(As + ra * 128 + ((((kk << 2) | lg) ^ (ra & 7)) << 4));
            }
            #pragma unroll
            for (int f = 0; f < 2; ++f) {
                int rb = wn * 32 + f * 16 + l15;
                bv[f] = *(const bf16x8*)(Bs + rb * 128 + ((((kk << 2) | lg) ^ (rb & 7)) << 4));
            }
            #pragma unroll
            for (int mf = 0; mf < 4; ++mf)
                #pragma unroll
                for (int nf = 0; nf < 2; ++nf)
                    acc[mf][nf] = __builtin_amdgcn_mfma_f32_16x16x32_bf16(
                        av[mf], bv[nf], acc[mf][nf], 0, 0, 0);
        }
        __syncthreads();
    }

    #pragma unroll
    for (int mf = 0; mf < 4; ++mf) {
        int m0 = bm + wm * 64 + mf * 16 + lg * 4;
        #pragma unroll
        for (int nf = 0; nf < 2; ++nf) {
            int n0 = bn + wn * 32 + nf * 16 + l15;
            if (mode == 0) {
                #pragma unroll
                for (int r = 0; r < 4; ++r)
                    Cf[(size_t)(m0 + r) * 2048 + n0] = acc[mf][nf][r];
            } else if (n0 < 2048) {
                #pragma unroll
                for (int r = 0; r < 4; ++r)
                    Cq[(size_t)(m0 + r) * 2048 + n0] = f2bf(acc[mf][nf][r]);
            } else if (n0 < 3072) {
                #pragma unroll
                for (int r = 0; r < 4; ++r)
                    Ck[(size_t)(m0 + r) * 1024 + (n0 - 2048)] = f2bf(acc[mf][nf][r]);
            } else {
                ushort4 u;
                u.x = f2bf(acc[mf][nf][0]); u.y = f2bf(acc[mf][nf][1]);
                u.z = f2bf(acc[mf][nf][2]); u.w = f2bf(acc[mf][nf][3]);
                *(ushort4*)&Cv[(size_t)(n0 - 3072) * 2048 + m0] = u;
            }
        }
    }
}

// ---------------------------------------------------------------------------
// In-place RoPE on bf16 P[T][H*128].
// ---------------------------------------------------------------------------
__global__ __launch_bounds__(256) void rope_bf16(
    unsigned short* __restrict__ P, const float* __restrict__ cosT,
    const float* __restrict__ sinT, int H)
{
    int idx = blockIdx.x * 256 + threadIdx.x;
    int d = idx & 63;
    int h = (idx >> 6) % H;
    int t = idx / (64 * H);
    float c = cosT[t * HDIM + d];
    float s = sinT[t * HDIM + d];
    unsigned short* row = P + (size_t)t * (H * HDIM) + h * HDIM;
    float x0 = bf2f((short)row[d]), x1 = bf2f((short)row[d + 64]);
    row[d]      = f2bf(x0 * c - x1 * s);
    row[d + 64] = f2bf(x1 * c + x0 * s);
}

// ---------------------------------------------------------------------------
// Split-K flash attention. R8: the diagonal segment (seg == qt>>3) also folds
// the 4 depth slots into its partial (m,l,O) -> combine no longer reads
// Q/Dk/Dv. 1280 near-uniform blocks, XCD-pinned by hk, long segments first.
// ---------------------------------------------------------------------------
__global__ __launch_bounds__(256, 4) void attn_seg(
    const unsigned short* __restrict__ Qb, const unsigned short* __restrict__ Kb,
    const unsigned short* __restrict__ Vt,
    const float* __restrict__ Dk, const float* __restrict__ Dv,
    unsigned short* __restrict__ Opart, float2* __restrict__ mlpart)
{
    __shared__ char Ks[2][8192];   // [32 keys][128 d] bf16, chunk ^= key&7
    __shared__ char Vs[2][8192];   // [128 d][32 keys] bf16 (64B rows), chunk ^= (d>>1)&3
    __shared__ char Ps[4096];      // 4 waves x [16 q][32 keys] bf16, chunk ^= (q>>1)&3

    const int bid = blockIdx.x;
    const int hk = bid & 7;                       // == XCD (round-robin dispatch)
    const int idx = bid >> 3;                     // 0..159
    const int hq = hk * 2 + (idx & 1);
    const int si = 79 - (idx >> 1);               // long segments first
    int qt, seg;
    if (si < 8)       { qt = si;            seg = 0; }
    else if (si < 24) { int v = si - 8;  qt = 8  + (v >> 1); seg = v & 1; }
    else if (si < 48) { int v = si - 24; int q3 = v / 3; qt = 16 + q3; seg = v - q3 * 3; }
    else              { int v = si - 48; qt = 24 + (v >> 2); seg = v & 3; }
    const int q0 = qt * 64;
    const int keys = q0 + 64;
    const int jbeg = seg * 512;
    const int jend = min(jbeg + 512, keys);

    const int tid = threadIdx.x;
    const int wv = tid >> 6, lane = tid & 63;
    const int l15 = lane & 15, lg = lane >> 4;
    const size_t DSTRIDE = (size_t)NHK * T_SEQ * HDIM;

    const int tq = q0 + wv * 16 + l15;     // softmax-domain q row (per lane)
    const int qmax = q0 + wv * 16 + 15;    // wave's max q

    // Q B-frag: lane l15 = q col, k = d = c*32 + lg*8 + j
    bf16x8 qf[4];
    {
        const unsigned short* qrow = Qb + (size_t)tq * DMODEL + hq * HDIM;
        #pragma unroll
        for (int c = 0; c < 4; ++c)
            qf[c] = *(const bf16x8*)(qrow + c * 32 + lg * 8);
    }

    f32x4 oacc[8];
    #pragma unroll
    for (int dt = 0; dt < 8; ++dt) oacc[dt] = (f32x4){0.f, 0.f, 0.f, 0.f};
    float m = -1e30f, l = 0.f;

    #define STAGE(J0, BUF)                                                        \
        {                                                                         \
            _Pragma("unroll")                                                     \
            for (int it = 0; it < 2; ++it) {                                      \
                int o = it * 4096 + tid * 16;                                     \
                int rk = o >> 8, ck = (o >> 4) & 15;                              \
                gload16((const char*)Kb +                                         \
                        (((size_t)((J0) + rk) * 1024 + hk * 128 +                 \
                          ((ck ^ (rk & 7)) << 3)) << 1),                          \
                        Ks[BUF] + it * 4096 + wv * 1024);                         \
                int rv = o >> 6, cv = (o >> 4) & 3;                               \
                gload16((const char*)Vt +                                         \
                        (((size_t)(hk * 128 + rv) * 2048 + (J0) +                 \
                          ((cv ^ ((rv >> 1) & 3)) << 3)) << 1),                   \
                        Vs[BUF] + it * 4096 + wv * 1024);                         \
            }                                                                     \
        }

    STAGE(jbeg, 0);
    __syncthreads();
    int buf = 0;

    for (int j0 = jbeg; j0 < jend; j0 += 32) {
        if (j0 + 32 < jend) STAGE(j0 + 32, buf ^ 1);   // prefetch next tile

        if (j0 <= qmax) {
            const char* ksb = Ks[buf];
            const char* vsb = Vs[buf];
            // ---- S^T = K Q : 2 key-subtiles x 4 d-chunks ----
            float p[2][4];
            #pragma unroll
            for (int s = 0; s < 2; ++s) {
                if (j0 + s * 16 <= qmax) {
                    f32x4 sa = (f32x4){0.f, 0.f, 0.f, 0.f};
                    int row = s * 16 + l15;                 // key row (A-frag)
                    #pragma unroll
                    for (int c = 0; c < 4; ++c) {
                        int ch = (c * 4 + lg) ^ (row & 7);
                        bf16x8 kf = *(const bf16x8*)(ksb + row * 256 + ch * 16);
                        sa = __builtin_amdgcn_mfma_f32_16x16x32_bf16(kf, qf[c], sa, 0, 0, 0);
                    }
                    #pragma unroll
                    for (int r = 0; r < 4; ++r) {
                        int key = j0 + s * 16 + lg * 4 + r;
                        p[s][r] = (key <= tq) ? sa[r] * ATT_SCALE : -1e30f;
                    }
                } else {
                    #pragma unroll
                    for (int r = 0; r < 4; ++r) p[s][r] = -1e30f;
                }
            }
            // ---- online softmax with defer-max (THR=8) ----
            float vmax = p[0][0];
            #pragma unroll
            for (int s = 0; s < 2; ++s)
                #pragma unroll
                for (int r = 0; r < 4; ++r) vmax = fmaxf(vmax, p[s][r]);
            vmax = fmaxf(vmax, __shfl_xor(vmax, 16));
            vmax = fmaxf(vmax, __shfl_xor(vmax, 32));
            if (!__all(vmax <= m + 8.0f)) {
                float mn = fmaxf(m, vmax);
                float rs = __expf(m - mn);
                m = mn;
                l *= rs;
                float rs_o[4];
                #pragma unroll
                for (int r = 0; r < 4; ++r) rs_o[r] = __shfl(rs, lg * 4 + r);
                #pragma unroll
                for (int dt = 0; dt < 8; ++dt)
                    #pragma unroll
                    for (int r = 0; r < 4; ++r) oacc[dt][r] *= rs_o[r];
            }
            float sum = 0.f;
            #pragma unroll
            for (int s = 0; s < 2; ++s)
                #pragma unroll
                for (int r = 0; r < 4; ++r) {
                    float pe = __expf(p[s][r] - m);
                    p[s][r] = pe;
                    sum += pe;
                }
            sum += __shfl_xor(sum, 16);
            sum += __shfl_xor(sum, 32);
            l += sum;

            // ---- P -> per-wave LDS: pack 4 keys into one ds_write_b64 ----
            char* pw = Ps + wv * 1024;
            #pragma unroll
            for (int s = 0; s < 2; ++s) {
                unsigned int lo = (unsigned int)f2bf(p[s][0]) |
                                  ((unsigned int)f2bf(p[s][1]) << 16);
                unsigned int hi = (unsigned int)f2bf(p[s][2]) |
                                  ((unsigned int)f2bf(p[s][3]) << 16);
                int kc = s * 2 + (lg >> 1);               // key chunk 0..3
                int ch = kc ^ ((l15 >> 1) & 3);
                uint2 u = make_uint2(lo, hi);
                *(uint2*)(pw + l15 * 64 + ch * 16 + (lg & 1) * 8) = u;
            }
            asm volatile("" ::: "memory");
            // ---- PV: O += P V ----
            {
                bf16x8 pa = *(const bf16x8*)(pw + l15 * 64 + ((lg ^ ((l15 >> 1) & 3)) << 4));
                #pragma unroll
                for (int dt = 0; dt < 8; ++dt) {
                    int rv = dt * 16 + l15;
                    bf16x8 vf = *(const bf16x8*)(vsb + rv * 64 + ((lg ^ ((rv >> 1) & 3)) << 4));
                    oacc[dt] = __builtin_amdgcn_mfma_f32_16x16x32_bf16(pa, vf, oacc[dt], 0, 0, 0);
                }
            }
        }
        __syncthreads();   // drains prefetch + guards LDS reuse
        buf ^= 1;
    }

    // ---- diagonal segment folds the 4 depth slots into its partial ----
    if (seg == (qt >> 3)) {
        float dl[NL];
        #pragma unroll
        for (int sl = 0; sl < NL; ++sl) {
            const float* kd = Dk + sl * DSTRIDE + ((size_t)hk * T_SEQ + tq) * HDIM;
            float a = 0.f;
            #pragma unroll
            for (int c = 0; c < 4; ++c) {
                const float* kc = kd + c * 32 + lg * 8;
                float4 v0 = *(const float4*)(kc);
                float4 v1 = *(const float4*)(kc + 4);
                a = fmaf(bf2f(qf[c][0]), v0.x, a);
                a = fmaf(bf2f(qf[c][1]), v0.y, a);
                a = fmaf(bf2f(qf[c][2]), v0.z, a);
                a = fmaf(bf2f(qf[c][3]), v0.w, a);
                a = fmaf(bf2f(qf[c][4]), v1.x, a);
                a = fmaf(bf2f(qf[c][5]), v1.y, a);
                a = fmaf(bf2f(qf[c][6]), v1.z, a);
                a = fmaf(bf2f(qf[c][7]), v1.w, a);
            }
            a += __shfl_xor(a, 16);
            a += __shfl_xor(a, 32);
            dl[sl] = a * ATT_SCALE;
        }
        float vm = fmaxf(fmaxf(dl[0], dl[1]), fmaxf(dl[2], dl[3]));
        float mn = fmaxf(m, vm);
        float rsd = __expf(m - mn);
        m = mn;
        float pd[NL];
        #pragma unroll
        for (int sl = 0; sl < NL; ++sl) pd[sl] = __expf(dl[sl] - mn);
        l = l * rsd + (pd[0] + pd[1] + pd[2] + pd[3]);
        float rs_o[4], pdo[NL][4];
        #pragma unroll
        for (int r = 0; r < 4; ++r) {
            rs_o[r] = __shfl(rsd, lg * 4 + r);
            #pragma unroll
            for (int sl = 0; sl < NL; ++sl) pdo[sl][r] = __shfl(pd[sl], lg * 4 + r);
        }
        #pragma unroll
        for (int r = 0; r < 4; ++r) {
            int t = q0 + wv * 16 + lg * 4 + r;
            #pragma unroll
            for (int dt = 0; dt < 8; ++dt) {
                const float* vb = Dv + ((size_t)hk * T_SEQ + t) * HDIM + dt * 16 + l15;
                float o = oacc[dt][r] * rs_o[r];
                o = fmaf(pdo[0][r], vb[0], o);
                o = fmaf(pdo[1][r], vb[DSTRIDE], o);
                o = fmaf(pdo[2][r], vb[2 * DSTRIDE], o);
                o = fmaf(pdo[3][r], vb[3 * DSTRIDE], o);
                oacc[dt][r] = o;
            }
        }
    }

    // ---- write partials (unnormalized O bf16, per-row m/l f32) ----
    const int p = (hq * 32 + qt) * 4 + seg;
    unsigned short* op = Opart + (size_t)p * 8192;
    #pragma unroll
    for (int r = 0; r < 4; ++r) {
        unsigned short* orow = op + (wv * 16 + lg * 4 + r) * 128;
        #pragma unroll
        for (int dt = 0; dt < 8; ++dt)
            orow[dt * 16 + l15] = f2bf(oacc[dt][r]);
    }
    if (lg == 0) mlpart[p * 64 + wv * 16 + l15] = make_float2(m, l);
    #undef STAGE
}

// ---------------------------------------------------------------------------
// Slim combine: merge <=4 segment partials per (hq, q-tile), normalize,
// write bf16 AO. Thread owns (row = tid/4, 32-d slice = tid&3).
// ---------------------------------------------------------------------------
__global__ __launch_bounds__(256) void attn_combine(
    const unsigned short* __restrict__ Opart, const float2* __restrict__ mlpart,
    unsigned short* __restrict__ AO)
{
    const int bid = blockIdx.x;                 // 512
    const int hq = bid & 15;
    const int qt = bid >> 4;                    // 0..31
    const int nseg = (qt >> 3) + 1;
    const int pbase = (hq * 32 + qt) * 4;
    const int tid = threadIdx.x;
    const int row = tid >> 2;                   // 0..63
    const int dp = tid & 3;                     // 32-d slice
    const int t = qt * 64 + row;

    float mi[4], li[4];
    float M = -1e30f;
    for (int i = 0; i < nseg; ++i) {
        float2 v = mlpart[(pbase + i) * 64 + row];
        mi[i] = v.x; li[i] = v.y;
        M = fmaxf(M, v.x);
    }
    float L = 0.f, w[4];
    for (int i = 0; i < nseg; ++i) {
        w[i] = __expf(mi[i] - M);
        L += w[i] * li[i];
    }
    float linv = 1.f / L;

    float o[32];
    #pragma unroll
    for (int j = 0; j < 32; ++j) o[j] = 0.f;
    for (int i = 0; i < nseg; ++i) {
        const unsigned short* opr = Opart + (size_t)(pbase + i) * 8192 + row * 128 + dp * 32;
        #pragma unroll
        for (int c = 0; c < 4; ++c) {
            bf16x8 v = *(const bf16x8*)(opr + c * 8);
            #pragma unroll
            for (int j = 0; j < 8; ++j)
                o[c * 8 + j] = fmaf(w[i], bf2f(v[j]), o[c * 8 + j]);
        }
    }
    unsigned short* orow = AO + (size_t)t * DMODEL + hq * HDIM + dp * 32;
    #pragma unroll
    for (int c = 0; c < 4; ++c) {
        bf16x8 v;
        #pragma unroll
        for (int j = 0; j < 8; ++j) v[j] = (short)f2bf(o[c * 8 + j] * linv);
        *(bf16x8*)(orow + c * 8) = v;
    }
}

// ---------------------------------------------------------------------------
extern "C" void kernel_launch(void* const* d_in, const int* in_sizes, int n_in,
                              void* d_out, int out_size, void* d_ws, size_t ws_size,
                              hipStream_t stream) {
    const float* x    = (const float*)d_in[0];
    const float* dk   = (const float*)d_in[1];
    const float* dv   = (const float*)d_in[2];
    const float* cosT = (const float*)d_in[3];
    const float* sinT = (const float*)d_in[4];
    const float* Wq   = (const float*)d_in[5];
    const float* Wk   = (const float*)d_in[6];
    const float* Wv   = (const float*)d_in[7];
    const float* Wo   = (const float*)d_in[8];
    float* out = (float*)d_out;

    unsigned short* xb    = (unsigned short*)d_ws;
    unsigned short* Qb    = xb + (size_t)4 * 1024 * 1024;
    unsigned short* Kb    = Qb + (size_t)4 * 1024 * 1024;
    unsigned short* Vt    = Kb + (size_t)2 * 1024 * 1024;
    unsigned short* WTp   = Vt + (size_t)2 * 1024 * 1024;
    unsigned short* WoT   = WTp + (size_t)8 * 1024 * 1024;
    unsigned short* Opart = WoT + (size_t)4 * 1024 * 1024;
    float2* mlpart = (float2*)(Opart + (size_t)2048 * 8192);
    unsigned short* AOb = xb;   // alias: xb dead after proj GEMM

    cast_f32_bf16<<<dim3(2048), 256, 0, stream>>>(x, xb);
    tcast<<<dim3(32, 32), 256, 0, stream>>>(Wq, WTp, 2048, 2048, 0);
    tcast<<<dim3(32, 16), 256, 0, stream>>>(Wk, WTp, 1024, 2048, 2048);
    tcast<<<dim3(32, 16), 256, 0, stream>>>(Wv, WTp, 1024, 2048, 3072);
    tcast<<<dim3(32, 32), 256, 0, stream>>>(Wo, WoT, 2048, 2048, 0);
    gemm_bt<<<dim3(64, 16), 256, 0, stream>>>(xb, WTp, nullptr, Qb, Kb, Vt, 1, DMODEL);
    rope_bf16<<<dim3(T_SEQ * NHQ * 64 / 256), 256, 0, stream>>>(Qb, cosT, sinT, NHQ);
    rope_bf16<<<dim3(T_SEQ * NHK * 64 / 256), 256, 0, stream>>>(Kb, cosT, sinT, NHK);
    attn_seg<<<dim3(1280), 256, 0, stream>>>(Qb, Kb, Vt, dk, dv, Opart, mlpart);
    attn_combine<<<dim3(512), 256, 0, stream>>>(Opart, mlpart, AOb);
    gemm_bt<<<dim3(32, 16), 256, 0, stream>>>(AOb, WoT, out, nullptr, nullptr, nullptr, 0, DMODEL);
}